// Round 8
// baseline (221.169 us; speedup 1.0000x reference)
//
#include <hip/hip_runtime.h>
#include <hip/hip_bf16.h>

#define EMBED 1024
#define HEAD 64
#define SEQ 4096

typedef __attribute__((ext_vector_type(8))) short short8;
typedef __attribute__((ext_vector_type(4))) float f32x4;

union S8u { short8 v; uint u[4]; ushort s[8]; };

// manual RNE f32->bf16 (flash PV path — round-3-proven numerics)
__device__ __forceinline__ ushort f2bf(float f) {
  union { float f; uint u; } x; x.f = f;
  return (ushort)((x.u + 0x7fffu + ((x.u >> 16) & 1u)) >> 16);
}

// native cast (proj/prep bulk conversion — compiler emits native cvt)
__device__ __forceinline__ ushort f2bf_n(float f) {
  union { __hip_bfloat16 h; ushort u; } cv;
  cv.h = __float2bfloat16(f);
  return cv.u;
}

__device__ __forceinline__ short8 ld16(const ushort* p) {
  uint4 q = *(const uint4*)p;
  S8u t; t.u[0] = q.x; t.u[1] = q.y; t.u[2] = q.z; t.u[3] = q.w;
  return t.v;
}

// ---------------- kernel 1: transpose weights to bf16 wT[t][c][k] ----------------
__global__ __launch_bounds__(256) void prep_w(const float* __restrict__ wq,
                                              const float* __restrict__ wk,
                                              const float* __restrict__ wv,
                                              ushort* __restrict__ wT) {
  int idx = blockIdx.x * 256 + threadIdx.x;
  if (idx >= 3 * HEAD * EMBED) return;
  int t = idx >> 16;
  int rem = idx & 0xFFFF;
  int c = rem >> 10;
  int k = rem & 1023;
  const float* w = (t == 0) ? wq : (t == 1) ? wk : wv;
  wT[idx] = f2bf_n(w[k * HEAD + c]);
}

// ------ kernel 2: projections -> q_bf16 (scale 0.125*log2e), k_bf16, v^T bf16 -----
__global__ __launch_bounds__(256) void proj_kernel(
    const float* __restrict__ qsrc, const float* __restrict__ ksrc,
    const float* __restrict__ vsrc, const ushort* __restrict__ wT,
    ushort* __restrict__ qb, ushort* __restrict__ kb, ushort* __restrict__ vt) {
  __shared__ ushort vtile[64][72];
  int t = blockIdx.y;
  const float* src = (t == 0) ? qsrc : (t == 1) ? ksrc : vsrc;
  const ushort* wt = wT + t * (HEAD * EMBED);
  int lane = threadIdx.x & 63;
  int wid = threadIdx.x >> 6;
  int c = lane & 15;
  int g = lane >> 4;
  int arow_i = blockIdx.x * 64 + wid * 16 + c;
  const float* arow = src + (size_t)arow_i * EMBED;

  f32x4 acc[4];
#pragma unroll
  for (int i = 0; i < 4; ++i) acc[i] = {0.f, 0.f, 0.f, 0.f};

#pragma unroll 8
  for (int k0 = 0; k0 < EMBED; k0 += 32) {
    float4 a0 = *(const float4*)(arow + k0 + 8 * g);
    float4 a1 = *(const float4*)(arow + k0 + 8 * g + 4);
    S8u a;
    a.s[0] = f2bf_n(a0.x); a.s[1] = f2bf_n(a0.y); a.s[2] = f2bf_n(a0.z); a.s[3] = f2bf_n(a0.w);
    a.s[4] = f2bf_n(a1.x); a.s[5] = f2bf_n(a1.y); a.s[6] = f2bf_n(a1.z); a.s[7] = f2bf_n(a1.w);
#pragma unroll
    for (int nf = 0; nf < 4; ++nf) {
      short8 b = ld16(wt + (size_t)(nf * 16 + c) * EMBED + k0 + 8 * g);
      acc[nf] = __builtin_amdgcn_mfma_f32_16x16x32_bf16(a.v, b, acc[nf], 0, 0, 0);
    }
  }

  if (t == 2) {
#pragma unroll
    for (int nf = 0; nf < 4; ++nf)
#pragma unroll
      for (int r = 0; r < 4; ++r)
        vtile[nf * 16 + c][wid * 16 + 4 * g + r] = f2bf_n(acc[nf][r]);
    __syncthreads();
    int d = threadIdx.x >> 2;
    int s0 = (threadIdx.x & 3) << 4;
    int row0 = blockIdx.x * 64;
    int bb = row0 >> 12;
    int sbase = row0 & (SEQ - 1);
    ushort* dst = vt + ((size_t)(bb * HEAD + d) << 12) + sbase + s0;
    const uint4* srcp = (const uint4*)&vtile[d][s0];
    *(uint4*)dst = srcp[0];
    *(uint4*)(dst + 8) = srcp[1];
  } else {
    int row_base = blockIdx.x * 64 + wid * 16 + 4 * g;
    float scale = (t == 0) ? 0.18033688011112042f : 1.0f;  // 0.125*log2(e)
    ushort* dstb = (t == 0) ? qb : kb;
#pragma unroll
    for (int nf = 0; nf < 4; ++nf)
#pragma unroll
      for (int r = 0; r < 4; ++r)
        dstb[(size_t)(row_base + r) * HEAD + nf * 16 + c] = f2bf_n(acc[nf][r] * scale);
  }
}

// -- kernel 3: flash attn partials — 32q band, 8 waves x 2 blocks = 16-way kv split --
//    round-3 body (64 VGPR), small-LDS atomic merge, partials to workspace
__global__ __launch_bounds__(512, 4) void flash_kernel(
    const ushort* __restrict__ qb, const ushort* __restrict__ kb,
    const ushort* __restrict__ vt, float* __restrict__ Opart,
    float* __restrict__ mlpart) {
  __shared__ float ml_s[8][32];     // per-wave running max m
  __shared__ float O_acc[32][68];   // 8.7 KB merge accumulator (padded)
  __shared__ float L_acc[32];

  const int tid = threadIdx.x;
  const int lane = tid & 63;
  const int w = tid >> 6;
  const int c = lane & 15, g = lane >> 4;

  const int bid = blockIdx.x;
  const int j = bid & 1;                  // kv-split block index
  const int b = (bid >> 1) & 3;
  const int band = 127 - (bid >> 3);      // LPT: longest bands first
  const int q0 = band << 5;
  const int nkt = ((q0 + 31) >> 6) + 1;   // 64-key tiles in causal range

  const ushort* kbb = kb + (size_t)b * SEQ * HEAD;
  const ushort* vtb = vt + (size_t)b * HEAD * SEQ;

  // Q fragments: query = q0 + 16qf + c, contiguous-8 k slots (pre-scaled)
  short8 qa[2][2];
#pragma unroll
  for (int qf = 0; qf < 2; ++qf) {
    const ushort* qrow = qb + (size_t)(b * SEQ + q0 + 16 * qf + c) * HEAD + 8 * g;
    qa[qf][0] = ld16(qrow);
    qa[qf][1] = ld16(qrow + 32);
  }

  f32x4 O[4][2];
#pragma unroll
  for (int i = 0; i < 4; ++i)
#pragma unroll
    for (int qf = 0; qf < 2; ++qf) O[i][qf] = {0.f, 0.f, 0.f, 0.f};
  float m[2] = {-1e30f, -1e30f};
  float l[2] = {0.f, 0.f};

  // wave slot s = 2w + j; tiles kt = s, s+16, ...
  for (int kt = 2 * w + j; kt < nkt; kt += 16) {
    int k0 = kt << 6;

    // ---- V loads issued first: latency hides under QK + softmax ----
    S8u vv[2][4];
#pragma unroll
    for (int sl = 0; sl < 2; ++sl)
#pragma unroll
      for (int nf = 0; nf < 4; ++nf) {
        const ushort* vrow = vtb + (size_t)(nf * 16 + c) * SEQ + k0 + 32 * sl + 4 * g;
        uint2 vlo = *(const uint2*)vrow;
        uint2 vhi = *(const uint2*)(vrow + 16);
        vv[sl][nf].u[0] = vlo.x; vv[sl][nf].u[1] = vlo.y;
        vv[sl][nf].u[2] = vhi.x; vv[sl][nf].u[3] = vhi.y;
      }

    // ---- S^T = K Q^T : frag [nf][qf]: key = k0+16nf+4g+rr, query = q0+16qf+c ----
    f32x4 Sf[4][2];
#pragma unroll
    for (int i = 0; i < 4; ++i)
#pragma unroll
      for (int qf = 0; qf < 2; ++qf) Sf[i][qf] = {0.f, 0.f, 0.f, 0.f};
#pragma unroll
    for (int nf = 0; nf < 4; ++nf) {
      const ushort* krow = kbb + (size_t)(k0 + nf * 16 + c) * HEAD + 8 * g;
      short8 ka0 = ld16(krow);
      short8 ka1 = ld16(krow + 32);
#pragma unroll
      for (int qf = 0; qf < 2; ++qf) {
        Sf[nf][qf] = __builtin_amdgcn_mfma_f32_16x16x32_bf16(ka0, qa[qf][0], Sf[nf][qf], 0, 0, 0);
        Sf[nf][qf] = __builtin_amdgcn_mfma_f32_16x16x32_bf16(ka1, qa[qf][1], Sf[nf][qf], 0, 0, 0);
      }
    }

    // ---- causal mask (only the diagonal tile) ----
    if (k0 + 63 > q0) {
#pragma unroll
      for (int nf = 0; nf < 4; ++nf)
#pragma unroll
        for (int qf = 0; qf < 2; ++qf)
#pragma unroll
          for (int rr = 0; rr < 4; ++rr)
            if (k0 + nf * 16 + 4 * g + rr > q0 + 16 * qf + c) Sf[nf][qf][rr] = -1e30f;
    }

    // ---- online softmax per q-frag (exp2 domain) ----
#pragma unroll
    for (int qf = 0; qf < 2; ++qf) {
      float x0 = fmaxf(fmaxf(Sf[0][qf][0], Sf[0][qf][1]), fmaxf(Sf[0][qf][2], Sf[0][qf][3]));
      float x1 = fmaxf(fmaxf(Sf[1][qf][0], Sf[1][qf][1]), fmaxf(Sf[1][qf][2], Sf[1][qf][3]));
      float x2 = fmaxf(fmaxf(Sf[2][qf][0], Sf[2][qf][1]), fmaxf(Sf[2][qf][2], Sf[2][qf][3]));
      float x3 = fmaxf(fmaxf(Sf[3][qf][0], Sf[3][qf][1]), fmaxf(Sf[3][qf][2], Sf[3][qf][3]));
      float rm = fmaxf(fmaxf(x0, x1), fmaxf(x2, x3));
      rm = fmaxf(rm, __shfl_xor(rm, 16));
      rm = fmaxf(rm, __shfl_xor(rm, 32));
      rm = fmaxf(rm, m[qf]);
      float alpha = exp2f(m[qf] - rm);
      m[qf] = rm;
#pragma unroll
      for (int nf = 0; nf < 4; ++nf)
#pragma unroll
        for (int rr = 0; rr < 4; ++rr)
          Sf[nf][qf][rr] = exp2f(Sf[nf][qf][rr] - rm);
      float s0 = (Sf[0][qf][0] + Sf[0][qf][1]) + (Sf[0][qf][2] + Sf[0][qf][3]);
      float s1 = (Sf[1][qf][0] + Sf[1][qf][1]) + (Sf[1][qf][2] + Sf[1][qf][3]);
      float s2 = (Sf[2][qf][0] + Sf[2][qf][1]) + (Sf[2][qf][2] + Sf[2][qf][3]);
      float s3 = (Sf[3][qf][0] + Sf[3][qf][1]) + (Sf[3][qf][2] + Sf[3][qf][3]);
      float rs = (s0 + s1) + (s2 + s3);
      rs += __shfl_xor(rs, 16);
      rs += __shfl_xor(rs, 32);
      l[qf] = l[qf] * alpha + rs;
#pragma unroll
      for (int nf = 0; nf < 4; ++nf)
#pragma unroll
        for (int rr = 0; rr < 4; ++rr)
          O[nf][qf][rr] *= alpha;
    }

    // ---- O^T += V^T P ----
#pragma unroll
    for (int qf = 0; qf < 2; ++qf)
#pragma unroll
      for (int sl = 0; sl < 2; ++sl) {
        S8u pa;
#pragma unroll
        for (int rr = 0; rr < 4; ++rr) {
          pa.s[rr]     = f2bf(Sf[2 * sl][qf][rr]);
          pa.s[rr + 4] = f2bf(Sf[2 * sl + 1][qf][rr]);
        }
#pragma unroll
        for (int nf = 0; nf < 4; ++nf)
          O[nf][qf] = __builtin_amdgcn_mfma_f32_16x16x32_bf16(vv[sl][nf].v, pa.v, O[nf][qf], 0, 0, 0);
      }
  }

  // ---- in-block merge: zero accumulators + publish per-wave m ----
  for (int i = tid; i < 32 * 68; i += 512) ((float*)O_acc)[i] = 0.f;
  if (tid < 32) L_acc[tid] = 0.f;
  if (g == 0) {
#pragma unroll
    for (int qf = 0; qf < 2; ++qf) ml_s[w][16 * qf + c] = m[qf];
  }
  __syncthreads();

  // ---- weighted atomic accumulate ----
#pragma unroll
  for (int qf = 0; qf < 2; ++qf) {
    int q = 16 * qf + c;
    float M = ml_s[0][q];
#pragma unroll
    for (int w2 = 1; w2 < 8; ++w2) M = fmaxf(M, ml_s[w2][q]);
    float aw = exp2f(m[qf] - M);   // idle wave: m=-1e30, M=-1e30 -> aw=1, adds 0
    if (g == 0) atomicAdd(&L_acc[q], aw * l[qf]);
#pragma unroll
    for (int nf = 0; nf < 4; ++nf)
#pragma unroll
      for (int rr = 0; rr < 4; ++rr)
        atomicAdd(&O_acc[q][16 * nf + 4 * g + rr], aw * O[nf][qf][rr]);
  }
  __syncthreads();

  // ---- write block partial (M, L, O) to workspace ----
  size_t pi = (size_t)(b * 128 + band) * 2 + j;
  {
    int q = tid >> 4;
    int dq = tid & 15;
    f32x4 o = *(const f32x4*)&O_acc[q][4 * dq];
    *(f32x4*)&Opart[pi * 2048 + q * 64 + 4 * dq] = o;
    if (tid < 32) {
      float M = ml_s[0][tid];
#pragma unroll
      for (int w2 = 1; w2 < 8; ++w2) M = fmaxf(M, ml_s[w2][tid]);
      mlpart[pi * 64 + tid * 2]     = M;
      mlpart[pi * 64 + tid * 2 + 1] = L_acc[tid];
    }
  }
}

// ---------------- kernel 4: merge the 2 kv-split partials per band ----------------
__global__ __launch_bounds__(256) void merge_kernel(const float* __restrict__ Opart,
                                                    const float* __restrict__ mlpart,
                                                    float* __restrict__ out) {
  int i = blockIdx.x * 256 + threadIdx.x;   // 262144 = 16384 rows x 16 d-quads
  int dq = i & 15;
  int row = i >> 4;                          // 0..16383 = b*4096 + qrow
  int qrow = row & 4095;
  int band = qrow >> 5;
  int q = qrow & 31;
  size_t pi = (size_t)((row >> 12) * 128 + band) * 2;

  float m0 = mlpart[pi * 64 + q * 2],       l0 = mlpart[pi * 64 + q * 2 + 1];
  float m1 = mlpart[(pi + 1) * 64 + q * 2], l1 = mlpart[(pi + 1) * 64 + q * 2 + 1];
  float M = fmaxf(m0, m1);
  float a0 = exp2f(m0 - M), a1 = exp2f(m1 - M);
  float L = a0 * l0 + a1 * l1;
  f32x4 o0 = *(const f32x4*)&Opart[pi * 2048 + q * 64 + 4 * dq];
  f32x4 o1 = *(const f32x4*)&Opart[(pi + 1) * 2048 + q * 64 + 4 * dq];
  float inv = 1.0f / L;
  f32x4 res;
#pragma unroll
  for (int rr = 0; rr < 4; ++rr) res[rr] = (a0 * o0[rr] + a1 * o1[rr]) * inv;
  *(f32x4*)&out[(size_t)row * HEAD + 4 * dq] = res;
}

extern "C" void kernel_launch(void* const* d_in, const int* in_sizes, int n_in,
                              void* d_out, int out_size, void* d_ws, size_t ws_size,
                              hipStream_t stream) {
  const float* qsrc = (const float*)d_in[0];
  const float* ksrc = (const float*)d_in[1];
  const float* vsrc = (const float*)d_in[2];
  const float* wq = (const float*)d_in[3];
  const float* wk = (const float*)d_in[4];
  const float* wv = (const float*)d_in[5];
  float* out = (float*)d_out;

  char* ws = (char*)d_ws;
  ushort* wT = (ushort*)ws;                                // 384 KB
  ushort* qb = (ushort*)(ws + 393216);                     // 2 MB
  ushort* kb = (ushort*)(ws + 393216 + 2097152);           // 2 MB
  ushort* vt = (ushort*)(ws + 393216 + 2 * 2097152);       // 2 MB (transposed V)
  float* Opart = (float*)(ws + 393216 + 3 * 2097152);      // 8.4 MB
  float* mlpart = (float*)(ws + 393216 + 3 * 2097152 + 8388608);  // 256 KB

  prep_w<<<dim3(768), dim3(256), 0, stream>>>(wq, wk, wv, wT);
  proj_kernel<<<dim3(256, 3), dim3(256), 0, stream>>>(qsrc, ksrc, vsrc, wT, qb, kb, vt);
  flash_kernel<<<dim3(1024), dim3(512), 0, stream>>>(qb, kb, vt, Opart, mlpart);
  merge_kernel<<<dim3(1024), dim3(256), 0, stream>>>(Opart, mlpart, out);
}

// Round 9
// 122.595 us; speedup vs baseline: 1.8041x; 1.8041x over previous
//
#include <hip/hip_runtime.h>
#include <hip/hip_bf16.h>

#define EMBED 1024
#define HEAD 64
#define SEQ 4096

typedef __attribute__((ext_vector_type(8))) short short8;
typedef __attribute__((ext_vector_type(4))) float f32x4;

union S8u { short8 v; uint u[4]; ushort s[8]; };

// manual RNE f32->bf16 (flash PV path — proven numerics)
__device__ __forceinline__ ushort f2bf(float f) {
  union { float f; uint u; } x; x.f = f;
  return (ushort)((x.u + 0x7fffu + ((x.u >> 16) & 1u)) >> 16);
}

// native cast (proj/prep bulk conversion)
__device__ __forceinline__ ushort f2bf_n(float f) {
  union { __hip_bfloat16 h; ushort u; } cv;
  cv.h = __float2bfloat16(f);
  return cv.u;
}

__device__ __forceinline__ short8 ld16(const ushort* p) {
  uint4 q = *(const uint4*)p;
  S8u t; t.u[0] = q.x; t.u[1] = q.y; t.u[2] = q.z; t.u[3] = q.w;
  return t.v;
}

// ---------------- kernel 1: transpose weights to bf16 wT[t][c][k] ----------------
__global__ __launch_bounds__(256) void prep_w(const float* __restrict__ wq,
                                              const float* __restrict__ wk,
                                              const float* __restrict__ wv,
                                              ushort* __restrict__ wT) {
  int idx = blockIdx.x * 256 + threadIdx.x;
  if (idx >= 3 * HEAD * EMBED) return;
  int t = idx >> 16;
  int rem = idx & 0xFFFF;
  int c = rem >> 10;
  int k = rem & 1023;
  const float* w = (t == 0) ? wq : (t == 1) ? wk : wv;
  wT[idx] = f2bf_n(w[k * HEAD + c]);
}

// ------ kernel 2: projections -> q_bf16 (scale 0.125*log2e), k_bf16, v^T bf16 -----
__global__ __launch_bounds__(256) void proj_kernel(
    const float* __restrict__ qsrc, const float* __restrict__ ksrc,
    const float* __restrict__ vsrc, const ushort* __restrict__ wT,
    ushort* __restrict__ qb, ushort* __restrict__ kb, ushort* __restrict__ vt) {
  __shared__ ushort vtile[64][72];
  int t = blockIdx.y;
  const float* src = (t == 0) ? qsrc : (t == 1) ? ksrc : vsrc;
  const ushort* wt = wT + t * (HEAD * EMBED);
  int lane = threadIdx.x & 63;
  int wid = threadIdx.x >> 6;
  int c = lane & 15;
  int g = lane >> 4;
  int arow_i = blockIdx.x * 64 + wid * 16 + c;
  const float* arow = src + (size_t)arow_i * EMBED;

  f32x4 acc[4];
#pragma unroll
  for (int i = 0; i < 4; ++i) acc[i] = {0.f, 0.f, 0.f, 0.f};

#pragma unroll 8
  for (int k0 = 0; k0 < EMBED; k0 += 32) {
    float4 a0 = *(const float4*)(arow + k0 + 8 * g);
    float4 a1 = *(const float4*)(arow + k0 + 8 * g + 4);
    S8u a;
    a.s[0] = f2bf_n(a0.x); a.s[1] = f2bf_n(a0.y); a.s[2] = f2bf_n(a0.z); a.s[3] = f2bf_n(a0.w);
    a.s[4] = f2bf_n(a1.x); a.s[5] = f2bf_n(a1.y); a.s[6] = f2bf_n(a1.z); a.s[7] = f2bf_n(a1.w);
#pragma unroll
    for (int nf = 0; nf < 4; ++nf) {
      short8 b = ld16(wt + (size_t)(nf * 16 + c) * EMBED + k0 + 8 * g);
      acc[nf] = __builtin_amdgcn_mfma_f32_16x16x32_bf16(a.v, b, acc[nf], 0, 0, 0);
    }
  }

  if (t == 2) {
#pragma unroll
    for (int nf = 0; nf < 4; ++nf)
#pragma unroll
      for (int r = 0; r < 4; ++r)
        vtile[nf * 16 + c][wid * 16 + 4 * g + r] = f2bf_n(acc[nf][r]);
    __syncthreads();
    int d = threadIdx.x >> 2;
    int s0 = (threadIdx.x & 3) << 4;
    int row0 = blockIdx.x * 64;
    int bb = row0 >> 12;
    int sbase = row0 & (SEQ - 1);
    ushort* dst = vt + ((size_t)(bb * HEAD + d) << 12) + sbase + s0;
    const uint4* srcp = (const uint4*)&vtile[d][s0];
    *(uint4*)dst = srcp[0];
    *(uint4*)(dst + 8) = srcp[1];
  } else {
    int row_base = blockIdx.x * 64 + wid * 16 + 4 * g;
    float scale = (t == 0) ? 0.18033688011112042f : 1.0f;  // 0.125*log2(e)
    ushort* dstb = (t == 0) ? qb : kb;
#pragma unroll
    for (int nf = 0; nf < 4; ++nf)
#pragma unroll
      for (int r = 0; r < 4; ++r)
        dstb[(size_t)(row_base + r) * HEAD + nf * 16 + c] = f2bf_n(acc[nf][r] * scale);
  }
}

// -- kernel 3: flash attn — 256-q block, 8 waves SHARE each staged KV tile (reuse x8),
//    4-way kv-chunk across blocks, partials to workspace. Body = round-5-proven.
__global__ __launch_bounds__(512, 2) void flash_kernel(
    const ushort* __restrict__ qb, const ushort* __restrict__ kb,
    const ushort* __restrict__ vt, float* __restrict__ Opart,
    float* __restrict__ mlpart) {
  __shared__ __align__(16) char smem[16384];   // K tile @0 (8KB), V tile @8192 (8KB)

  const int tid = threadIdx.x;
  const int lane = tid & 63;
  const int w = tid >> 6;
  const int c = lane & 15, g = lane >> 4;

  // grid 256 = 16 band-ranks x 4 batches x 4 kv-chunks; LPT: big bands first
  const int bid = blockIdx.x;
  const int band = 15 - (bid >> 4);
  const int b = (bid >> 2) & 3;
  const int j = bid & 3;
  const int ck = band + 1;          // tiles per chunk (exact: nkt_block = 4*(band+1))
  const int kt0 = j * ck;
  const int q0w = band * 256 + w * 32;    // this wave's 32 q-rows

  // staging: thread covers 16B of each 64x128B tile (K and V alike)
  const int srow = tid >> 3;
  const int scol = (tid & 7) << 4;
  const int sdst = srow * 128 + (scol ^ ((srow & 7) << 4));   // XOR-swizzled dest
  const char* kgp = (const char*)(kb + (size_t)b * SEQ * HEAD) + (size_t)kt0 * 8192 + tid * 16;
  const char* vgp = (const char*)(vt + (size_t)b * HEAD * SEQ) + (size_t)srow * 8192 + kt0 * 128 + scol;

  // Q fragments: query = q0w + 16qf + c (pre-scaled by 0.125*log2e)
  short8 qa[2][2];
#pragma unroll
  for (int qf = 0; qf < 2; ++qf) {
    const ushort* qrow = qb + (size_t)(b * SEQ + q0w + 16 * qf + c) * HEAD + 8 * g;
    qa[qf][0] = ld16(qrow);
    qa[qf][1] = ld16(qrow + 32);
  }

  f32x4 O[4][2];
#pragma unroll
  for (int i = 0; i < 4; ++i)
#pragma unroll
    for (int qf = 0; qf < 2; ++qf) O[i][qf] = {0.f, 0.f, 0.f, 0.f};
  float m[2] = {-1e30f, -1e30f};
  float l[2] = {0.f, 0.f};

  // prologue: loads for first tile
  uint4 sK = *(const uint4*)kgp;
  uint4 sV = *(const uint4*)vgp;

  for (int r = 0; r < ck; ++r) {
    // ---- write staged regs to LDS ----
    *(uint4*)(smem + sdst) = sK;
    *(uint4*)(smem + 8192 + sdst) = sV;
    __syncthreads();

    // ---- issue next tile's loads (hidden under compute) ----
    if (r + 1 < ck) {
      kgp += 8192; vgp += 128;
      sK = *(const uint4*)kgp;
      sV = *(const uint4*)vgp;
    }

    const int kt = kt0 + r;
    const int k0 = kt << 6;
    if (k0 <= q0w + 31) {   // tile intersects this wave's causal range
      // ---- S^T = K Q^T (K from LDS) ----
      f32x4 Sf[4][2];
#pragma unroll
      for (int i = 0; i < 4; ++i)
#pragma unroll
        for (int qf = 0; qf < 2; ++qf) Sf[i][qf] = {0.f, 0.f, 0.f, 0.f};
#pragma unroll
      for (int nf = 0; nf < 4; ++nf) {
        int row = 16 * nf + c;
        int sw = (row & 7) << 4;
        uint4 kv = *(const uint4*)(smem + row * 128 + ((16 * g) ^ sw));
        S8u ka0;
        ka0.u[0] = kv.x; ka0.u[1] = kv.y; ka0.u[2] = kv.z; ka0.u[3] = kv.w;
#pragma unroll
        for (int qf = 0; qf < 2; ++qf)
          Sf[nf][qf] = __builtin_amdgcn_mfma_f32_16x16x32_bf16(ka0.v, qa[qf][0], Sf[nf][qf], 0, 0, 0);
        uint4 kv2 = *(const uint4*)(smem + row * 128 + ((64 + 16 * g) ^ sw));
        S8u ka1;
        ka1.u[0] = kv2.x; ka1.u[1] = kv2.y; ka1.u[2] = kv2.z; ka1.u[3] = kv2.w;
#pragma unroll
        for (int qf = 0; qf < 2; ++qf)
          Sf[nf][qf] = __builtin_amdgcn_mfma_f32_16x16x32_bf16(ka1.v, qa[qf][1], Sf[nf][qf], 0, 0, 0);
      }

      // ---- causal mask (only diagonal-crossing tiles) ----
      if (k0 + 63 > q0w) {
#pragma unroll
        for (int nf = 0; nf < 4; ++nf)
#pragma unroll
          for (int qf = 0; qf < 2; ++qf)
#pragma unroll
            for (int rr = 0; rr < 4; ++rr)
              if (k0 + nf * 16 + 4 * g + rr > q0w + 16 * qf + c) Sf[nf][qf][rr] = -1e30f;
      }

      // ---- online softmax (exp2 domain, per-tile rescale) + PV ----
#pragma unroll
      for (int qf = 0; qf < 2; ++qf) {
        float x0 = fmaxf(fmaxf(Sf[0][qf][0], Sf[0][qf][1]), fmaxf(Sf[0][qf][2], Sf[0][qf][3]));
        float x1 = fmaxf(fmaxf(Sf[1][qf][0], Sf[1][qf][1]), fmaxf(Sf[1][qf][2], Sf[1][qf][3]));
        float x2 = fmaxf(fmaxf(Sf[2][qf][0], Sf[2][qf][1]), fmaxf(Sf[2][qf][2], Sf[2][qf][3]));
        float x3 = fmaxf(fmaxf(Sf[3][qf][0], Sf[3][qf][1]), fmaxf(Sf[3][qf][2], Sf[3][qf][3]));
        float rm = fmaxf(fmaxf(x0, x1), fmaxf(x2, x3));
        rm = fmaxf(rm, __shfl_xor(rm, 16));
        rm = fmaxf(rm, __shfl_xor(rm, 32));
        rm = fmaxf(rm, m[qf]);
        float alpha = exp2f(m[qf] - rm);
        m[qf] = rm;
#pragma unroll
        for (int nf = 0; nf < 4; ++nf)
#pragma unroll
          for (int rr = 0; rr < 4; ++rr)
            Sf[nf][qf][rr] = exp2f(Sf[nf][qf][rr] - rm);
        float s0 = (Sf[0][qf][0] + Sf[0][qf][1]) + (Sf[0][qf][2] + Sf[0][qf][3]);
        float s1 = (Sf[1][qf][0] + Sf[1][qf][1]) + (Sf[1][qf][2] + Sf[1][qf][3]);
        float s2 = (Sf[2][qf][0] + Sf[2][qf][1]) + (Sf[2][qf][2] + Sf[2][qf][3]);
        float s3 = (Sf[3][qf][0] + Sf[3][qf][1]) + (Sf[3][qf][2] + Sf[3][qf][3]);
        float rs = (s0 + s1) + (s2 + s3);
        rs += __shfl_xor(rs, 16);
        rs += __shfl_xor(rs, 32);
        l[qf] = l[qf] * alpha + rs;
#pragma unroll
        for (int nf = 0; nf < 4; ++nf)
#pragma unroll
          for (int rr = 0; rr < 4; ++rr)
            O[nf][qf][rr] *= alpha;

        // O^T += V^T P (V from LDS; P already in B-fragment layout)
#pragma unroll
        for (int sl = 0; sl < 2; ++sl) {
          S8u pa;
#pragma unroll
          for (int rr = 0; rr < 4; ++rr) {
            pa.s[rr]     = f2bf(Sf[2 * sl][qf][rr]);
            pa.s[rr + 4] = f2bf(Sf[2 * sl + 1][qf][rr]);
          }
#pragma unroll
          for (int nf = 0; nf < 4; ++nf) {
            int row = 16 * nf + c;
            int sw = (row & 7) << 4;
            S8u vbf;
            uint2 lo = *(const uint2*)(smem + 8192 + row * 128 + ((64 * sl + 8 * g) ^ sw));
            uint2 hi = *(const uint2*)(smem + 8192 + row * 128 + ((64 * sl + 32 + 8 * g) ^ sw));
            vbf.u[0] = lo.x; vbf.u[1] = lo.y; vbf.u[2] = hi.x; vbf.u[3] = hi.y;
            O[nf][qf] = __builtin_amdgcn_mfma_f32_16x16x32_bf16(vbf.v, pa.v, O[nf][qf], 0, 0, 0);
          }
        }
      }
    }
    __syncthreads();
  }

  // ---- write this wave's partial (owns its 32 q exclusively; no in-block merge) ----
  const size_t pi = (size_t)((b * 16 + band) * 4 + j);
#pragma unroll
  for (int qf = 0; qf < 2; ++qf) {
    int ql = w * 32 + 16 * qf + c;   // q within band
#pragma unroll
    for (int nf = 0; nf < 4; ++nf)
      *(f32x4*)&Opart[pi * 16384 + (size_t)ql * 64 + 16 * nf + 4 * g] = O[nf][qf];
    if (g == 0) {
      mlpart[pi * 512 + ql * 2]     = m[qf];
      mlpart[pi * 512 + ql * 2 + 1] = l[qf];
    }
  }
}

// ---------------- kernel 4: merge the 4 kv-chunk partials per band ----------------
__global__ __launch_bounds__(256) void merge_kernel(const float* __restrict__ Opart,
                                                    const float* __restrict__ mlpart,
                                                    float* __restrict__ out) {
  int i = blockIdx.x * 256 + threadIdx.x;   // 262144 = 16384 rows x 16 d-quads
  int dq = i & 15;
  int row = i >> 4;                          // b*4096 + qrow
  int b = row >> 12;
  int qrow = row & 4095;
  int band = qrow >> 8;
  int q = qrow & 255;
  size_t pi0 = (size_t)((b * 16 + band) * 4);

  float mm[4], M = -1e30f;
#pragma unroll
  for (int jj = 0; jj < 4; ++jj) { mm[jj] = mlpart[(pi0 + jj) * 512 + q * 2]; M = fmaxf(M, mm[jj]); }
  float wgt[4], L = 0.f;
#pragma unroll
  for (int jj = 0; jj < 4; ++jj) {
    wgt[jj] = exp2f(mm[jj] - M);   // idle chunks: exp2(-1e30 - M) -> 0
    L += wgt[jj] * mlpart[(pi0 + jj) * 512 + q * 2 + 1];
  }
  f32x4 acc = {0.f, 0.f, 0.f, 0.f};
#pragma unroll
  for (int jj = 0; jj < 4; ++jj) {
    f32x4 t = *(const f32x4*)&Opart[(pi0 + jj) * 16384 + (size_t)q * 64 + 4 * dq];
#pragma unroll
    for (int rr = 0; rr < 4; ++rr) acc[rr] += wgt[jj] * t[rr];
  }
  float inv = 1.0f / L;
  f32x4 res;
#pragma unroll
  for (int rr = 0; rr < 4; ++rr) res[rr] = acc[rr] * inv;
  *(f32x4*)&out[(size_t)row * HEAD + 4 * dq] = res;
}

extern "C" void kernel_launch(void* const* d_in, const int* in_sizes, int n_in,
                              void* d_out, int out_size, void* d_ws, size_t ws_size,
                              hipStream_t stream) {
  const float* qsrc = (const float*)d_in[0];
  const float* ksrc = (const float*)d_in[1];
  const float* vsrc = (const float*)d_in[2];
  const float* wq = (const float*)d_in[3];
  const float* wk = (const float*)d_in[4];
  const float* wv = (const float*)d_in[5];
  float* out = (float*)d_out;

  char* ws = (char*)d_ws;
  ushort* wT = (ushort*)ws;                                // 384 KB
  ushort* qb = (ushort*)(ws + 393216);                     // 2 MB
  ushort* kb = (ushort*)(ws + 393216 + 2097152);           // 2 MB
  ushort* vt = (ushort*)(ws + 393216 + 2 * 2097152);       // 2 MB (transposed V)
  float* Opart = (float*)(ws + 393216 + 3 * 2097152);      // 16 MB (256 partials x 256q x 64d)
  float* mlpart = (float*)(ws + 393216 + 3 * 2097152 + 16777216);  // 512 KB

  prep_w<<<dim3(768), dim3(256), 0, stream>>>(wq, wk, wv, wT);
  proj_kernel<<<dim3(256, 3), dim3(256), 0, stream>>>(qsrc, ksrc, vsrc, wT, qb, kb, vt);
  flash_kernel<<<dim3(256), dim3(512), 0, stream>>>(qb, kb, vt, Opart, mlpart);
  merge_kernel<<<dim3(1024), dim3(256), 0, stream>>>(Opart, mlpart, out);
}